// Round 3
// baseline (1930.334 us; speedup 1.0000x reference)
//
#include <hip/hip_runtime.h>
#include <math.h>

#define TT 2048
#define DM 2048
#define NHD 16
#define NKV 4
#define HDIM 128
#define NI 1024
#define ATT_SCALE 0.08838834764831845f

typedef unsigned short u16;
typedef __attribute__((ext_vector_type(8))) short short8;
typedef __attribute__((ext_vector_type(4))) short short4v;
typedef __attribute__((ext_vector_type(4))) float float4v;

#define AS1 __attribute__((address_space(1)))
#define AS3 __attribute__((address_space(3)))

__device__ __forceinline__ u16 f2bf(float f) {
  union { float f; unsigned u; } v; v.f = f;
  unsigned r = v.u + 0x7fffu + ((v.u >> 16) & 1u);
  return (u16)(r >> 16);
}
__device__ __forceinline__ float bf2f(u16 h) {
  union { unsigned u; float f; } v; v.u = ((unsigned)h) << 16;
  return v.f;
}
__device__ __forceinline__ float4v mfma16(short8 a, short8 b, float4v c) {
  return __builtin_amdgcn_mfma_f32_16x16x32_bf16(a, b, c, 0, 0, 0);
}
__device__ __forceinline__ void gl_lds(const u16* g, u16* l) {
  __builtin_amdgcn_global_load_lds((const AS1 void*)g, (AS3 void*)l, 16, 0, 0);
}

// ---------------- weight conversion ----------------
__global__ void cvt_split(const float* __restrict__ s, u16* __restrict__ oh,
                          u16* __restrict__ ol, int n) {
  int i = (blockIdx.x * 256 + threadIdx.x) * 4;
  if (i >= n) return;
  float4v v = *(const float4v*)(s + i);
  short4v vh, vl;
  #pragma unroll
  for (int c = 0; c < 4; ++c) {
    u16 hb = f2bf(v[c]);
    vh[c] = (short)hb;
    vl[c] = (short)f2bf(v[c] - bf2f(hb));
  }
  *(short4v*)(oh + i) = vh;
  *(short4v*)(ol + i) = vl;
}

__global__ void cvt_plain(const float* __restrict__ s, u16* __restrict__ o, int n) {
  int i = (blockIdx.x * 256 + threadIdx.x) * 8;
  if (i >= n) return;
  float4v v0 = *(const float4v*)(s + i);
  float4v v1 = *(const float4v*)(s + i + 4);
  short8 ov;
  #pragma unroll
  for (int c = 0; c < 4; ++c) {
    ov[c] = (short)f2bf(v0[c]);
    ov[c + 4] = (short)f2bf(v1[c]);
  }
  *(short8*)(o + i) = ov;
}

// ---------------- RMSNorm (row = 2048) ----------------
__global__ void rms_kernel(const float* __restrict__ in, const float* __restrict__ w,
                           u16* oh, u16* ol, float* of, u16* ob) {
  const int row = blockIdx.x, tid = threadIdx.x;
  const int lane = tid & 63, wvi = tid >> 6;
  const float* xr = in + (long)row * DM;
  float4v a = *(const float4v*)(xr + tid * 4);
  float4v b = *(const float4v*)(xr + 1024 + tid * 4);
  float ss = a[0]*a[0] + a[1]*a[1] + a[2]*a[2] + a[3]*a[3]
           + b[0]*b[0] + b[1]*b[1] + b[2]*b[2] + b[3]*b[3];
  #pragma unroll
  for (int m = 1; m < 64; m <<= 1) ss += __shfl_xor(ss, m);
  __shared__ float red[4];
  if (lane == 0) red[wvi] = ss;
  __syncthreads();
  float tot = red[0] + red[1] + red[2] + red[3];
  float sc = 1.0f / sqrtf(tot * (1.0f / 2048.0f) + 1e-5f);
  float4v w0 = *(const float4v*)(w + tid * 4);
  float4v w1 = *(const float4v*)(w + 1024 + tid * 4);
  #pragma unroll
  for (int c = 0; c < 4; ++c) {
    float v0 = a[c] * sc * w0[c];
    float v1 = b[c] * sc * w1[c];
    long i0 = (long)row * DM + tid * 4 + c;
    long i1 = i0 + 1024;
    if (oh) {
      u16 h0 = f2bf(v0); oh[i0] = h0; ol[i0] = f2bf(v0 - bf2f(h0));
      u16 h1 = f2bf(v1); oh[i1] = h1; ol[i1] = f2bf(v1 - bf2f(h1));
    }
    if (of) { of[i0] = v0; of[i1] = v1; }
    if (ob) { ob[i0] = f2bf(v0); ob[i1] = f2bf(v1); }
  }
}

// ---------------- per-head RMSNorm + RoPE ----------------
__global__ void rope_kernel(const float* __restrict__ qlin, const float* __restrict__ klin,
                            const float* __restrict__ qw, const float* __restrict__ kw,
                            u16* qh, u16* ql, u16* kh, u16* kl) {
  int rw = blockIdx.x * 4 + (threadIdx.x >> 6);
  int lane = threadIdx.x & 63;
  int t = rw / 20, hh = rw - t * 20;
  const float* src; const float* nw; u16 *dh, *dl;
  if (hh < 16) {
    long ofs = (long)t * 2048 + hh * 128;
    src = qlin + ofs; nw = qw; dh = qh + ofs; dl = ql + ofs;
  } else {
    long ofs = (long)t * 512 + (hh - 16) * 128;
    src = klin + ofs; nw = kw; dh = kh + ofs; dl = kl + ofs;
  }
  float x1 = src[lane], x2 = src[lane + 64];
  float ss = x1 * x1 + x2 * x2;
  #pragma unroll
  for (int m = 1; m < 64; m <<= 1) ss += __shfl_xor(ss, m);
  float sc = 1.0f / sqrtf(ss * (1.0f / 128.0f) + 1e-5f);
  x1 *= sc * nw[lane];
  x2 *= sc * nw[lane + 64];
  double inv = pow(1.0e6, -(double)lane * (1.0 / 64.0));
  double ang = (double)t * inv;
  float cs = (float)cos(ang), sn = (float)sin(ang);
  float o1 = x1 * cs - x2 * sn;
  float o2 = x2 * cs + x1 * sn;
  u16 hb1 = f2bf(o1); dh[lane] = hb1;      dl[lane] = f2bf(o1 - bf2f(hb1));
  u16 hb2 = f2bf(o2); dh[lane + 64] = hb2; dl[lane + 64] = f2bf(o2 - bf2f(hb2));
}

// ---------------- GEMM: C[M,N] = A[M,K] * B[N,K]^T ----------------
struct GemmP {
  const u16* Ah; long aloOff;
  const u16* B0h; const u16* B1h; long blo0; long blo1; long bstride; int ns0;
  int K;
  const int* permA; const int* cnt; const int* offs;
  int fixedM; int maxRow;
  float* oF; int ldF;
  float* oF2; int ldF2; int osplit;
  u16* oB; long oBlo; int ldB;
  const float* addX;
  const u16* dslots; const int* inv;
};

template<int EPI, bool SPLIT>
__launch_bounds__(256, 2)
__global__ void gemm_bt(GemmP p) {
  const int e = blockIdx.z;
  const int cnt = p.cnt ? p.cnt[e] : p.fixedM;
  const int mt0 = blockIdx.x * 128;
  if (mt0 >= cnt) return;
  const int off = p.offs ? p.offs[e] : 0;
  const int nt0 = blockIdx.y * 128;

  __shared__ u16 lAh[128 * 64];
  __shared__ u16 lBh[128 * 64];
  __shared__ u16 lAl[SPLIT ? 128 * 64 : 8];
  __shared__ u16 lBl[SPLIT ? 128 * 64 : 8];

  const int tid = threadIdx.x;
  const int lane = tid & 63, wvi = tid >> 6;
  const int quad = lane >> 4, l16 = lane & 15;
  const int wm = (wvi >> 1) * 64, wn = (wvi & 1) * 64;
  const int srow = tid >> 3;                 // 0..31
  const int scc = (tid & 7) ^ (srow & 7);    // logical chunk for staging

  const u16* agp[4];
  #pragma unroll
  for (int i = 0; i < 4; ++i) {
    int m = mt0 + i * 32 + srow;
    int r = off + m; if (r > p.maxRow) r = p.maxRow;
    if (p.permA) r = p.permA[r];
    agp[i] = p.Ah + (long)r * p.K + scc * 8;
  }
  const u16* bgph[4]; const u16* bgpl[4];
  #pragma unroll
  for (int j = 0; j < 4; ++j) {
    int n = nt0 + j * 32 + srow;
    const u16* bp; long lo;
    if (n < p.ns0) { bp = p.B0h + (long)e * p.bstride + (long)n * p.K; lo = p.blo0; }
    else           { bp = p.B1h + (long)e * p.bstride + (long)(n - p.ns0) * p.K; lo = p.blo1; }
    bgph[j] = bp + scc * 8;
    bgpl[j] = bp + lo + scc * 8;
  }

  float4v acc[4][4];
  #pragma unroll
  for (int a = 0; a < 4; ++a)
    #pragma unroll
    for (int b = 0; b < 4; ++b)
      acc[a][b] = (float4v){0.f, 0.f, 0.f, 0.f};

  const int wofs = wvi * 64 * 8;

  for (int k0 = 0; k0 < p.K; k0 += 64) {
    __syncthreads();
    #pragma unroll
    for (int i = 0; i < 4; ++i) {
      gl_lds(agp[i] + k0, &lAh[i * 2048 + wofs]);
      if constexpr (SPLIT) gl_lds(agp[i] + p.aloOff + k0, &lAl[i * 2048 + wofs]);
    }
    #pragma unroll
    for (int j = 0; j < 4; ++j) {
      gl_lds(bgph[j] + k0, &lBh[j * 2048 + wofs]);
      if constexpr (SPLIT) gl_lds(bgpl[j] + k0, &lBl[j * 2048 + wofs]);
    }
    __syncthreads();
    #pragma unroll
    for (int kc = 0; kc < 2; ++kc) {
      short8 ah[4], al[4], bh[4], bl[4];
      #pragma unroll
      for (int t = 0; t < 4; ++t) {
        int m = wm + t * 16 + l16;
        int ia = (m * 8 + ((kc * 4 + quad) ^ (m & 7))) * 8;
        ah[t] = *(const short8*)&lAh[ia];
        if constexpr (SPLIT) al[t] = *(const short8*)&lAl[ia];
        int n = wn + t * 16 + l16;
        int ib = (n * 8 + ((kc * 4 + quad) ^ (n & 7))) * 8;
        bh[t] = *(const short8*)&lBh[ib];
        if constexpr (SPLIT) bl[t] = *(const short8*)&lBl[ib];
      }
      #pragma unroll
      for (int mt = 0; mt < 4; ++mt)
        #pragma unroll
        for (int nt = 0; nt < 4; ++nt) {
          acc[mt][nt] = mfma16(ah[mt], bh[nt], acc[mt][nt]);
          if constexpr (SPLIT) {
            acc[mt][nt] = mfma16(ah[mt], bl[nt], acc[mt][nt]);
            acc[mt][nt] = mfma16(al[mt], bh[nt], acc[mt][nt]);
          }
        }
    }
  }

  #pragma unroll
  for (int mt = 0; mt < 4; ++mt) {
    #pragma unroll
    for (int nt = 0; nt < 4; ++nt) {
      const int n = nt0 + wn + nt * 16 + l16;
      const int mlb = wm + mt * 16 + quad * 4;
      if constexpr (EPI == 1) {            // transposed bf16 split store (vT)
        short4v vh, vl;
        #pragma unroll
        for (int r = 0; r < 4; ++r) {
          float v = acc[mt][nt][r];
          u16 hb = f2bf(v);
          vh[r] = (short)hb;
          vl[r] = (short)f2bf(v - bf2f(hb));
        }
        long ix = (long)n * p.ldB + (mt0 + mlb);
        *(short4v*)&p.oB[ix] = vh;
        *(short4v*)&p.oB[ix + p.oBlo] = vl;
      } else {
        #pragma unroll
        for (int r = 0; r < 4; ++r) {
          const int gm = mt0 + mlb + r;
          if (gm >= cnt) continue;
          float v = acc[mt][nt][r];
          if constexpr (EPI == 0) {        // f32, two-way column-split output
            if (n < p.osplit) p.oF[(long)gm * p.ldF + n] = v;
            else p.oF2[(long)gm * p.ldF2 + (n - p.osplit)] = v;
          } else if constexpr (EPI == 2) { // + residual x -> f32
            long ix = (long)gm * p.ldF + n;
            p.oF[ix] = v + p.addX[ix];
          } else if constexpr (EPI == 3) { // bf16 (rows offset by expert base)
            p.oB[(long)(off + gm) * p.ldB + n] = f2bf(v);
          } else if constexpr (EPI == 5) { // final: + h1 + 4-slot MoE gather
            long ix = (long)gm * p.ldF + n;
            const int* iv = p.inv + gm * 4;
            float s = bf2f(p.dslots[(long)iv[0] * DM + n])
                    + bf2f(p.dslots[(long)iv[1] * DM + n])
                    + bf2f(p.dslots[(long)iv[2] * DM + n])
                    + bf2f(p.dslots[(long)iv[3] * DM + n]);
            p.oF[ix] = v + p.addX[ix] + s;
          }
        }
      }
    }
  }
}

// ---------------- flash attention (causal, GQA 4:1, split-bf16) ----------------
// Barrier-free: per-wave q-strip (32 rows), K/V fragments loaded directly
// global->VGPR (16B contiguous), P transposed through per-wave private LDS.
__launch_bounds__(256, 2)
__global__ void attn_kernel(const u16* __restrict__ qh, const u16* __restrict__ ql,
                            const u16* __restrict__ kh, const u16* __restrict__ kl,
                            const u16* __restrict__ vh, const u16* __restrict__ vl,
                            u16* __restrict__ oh, u16* __restrict__ ol) {
  const int head = blockIdx.x;
  const int qt = (int)gridDim.y - 1 - blockIdx.y;   // long blocks first
  const int kvh = head >> 2;
  const int tid = threadIdx.x;
  const int lane = tid & 63, wvi = tid >> 6;
  const int quad = lane >> 4, l16 = lane & 15;

  __shared__ u16 lP[4][2][32 * 64];   // per-wave private P (hi/lo), swizzled
  u16* Ph = &lP[wvi][0][0];
  u16* Pl = &lP[wvi][1][0];

  const int qbase = qt * 128;
  short8 qfh[2][4], qfl[2][4];
  #pragma unroll
  for (int mt = 0; mt < 2; ++mt) {
    int row = qbase + wvi * 32 + mt * 16 + l16;
    const u16* ph = qh + (long)row * (NHD * HDIM) + head * HDIM + quad * 8;
    const u16* pl = ql + (long)row * (NHD * HDIM) + head * HDIM + quad * 8;
    #pragma unroll
    for (int kc = 0; kc < 4; ++kc) {
      qfh[mt][kc] = *(const short8*)(ph + kc * 32);
      qfl[mt][kc] = *(const short8*)(pl + kc * 32);
    }
  }
  float4v oacc[2][8];
  #pragma unroll
  for (int mt = 0; mt < 2; ++mt)
    #pragma unroll
    for (int dt = 0; dt < 8; ++dt)
      oacc[mt][dt] = (float4v){0.f, 0.f, 0.f, 0.f};
  float mrun[2][4], lrun[2][4];
  #pragma unroll
  for (int mt = 0; mt < 2; ++mt)
    #pragma unroll
    for (int r = 0; r < 4; ++r) { mrun[mt][r] = -INFINITY; lrun[mt][r] = 0.f; }

  const long kdiff = kl - kh;            // hi->lo plane offset (elements)
  const long vdiff = vl - vh;
  const int nsteps = 2 * qt + 2;

  for (int kt = 0; kt < nsteps; ++kt) {
    const int t0 = kt * 64;

    // ---- S = Q K^T (split 3-product), K frags direct from global ----
    float4v s[2][4];
    #pragma unroll
    for (int mt = 0; mt < 2; ++mt)
      #pragma unroll
      for (int nt = 0; nt < 4; ++nt)
        s[mt][nt] = (float4v){0.f, 0.f, 0.f, 0.f};
    #pragma unroll
    for (int nt = 0; nt < 4; ++nt) {
      const u16* krow = kh + (long)(t0 + nt * 16 + l16) * (NKV * HDIM)
                           + kvh * HDIM + quad * 8;
      #pragma unroll
      for (int kc = 0; kc < 4; ++kc) {
        short8 bh = *(const short8*)(krow + kc * 32);
        short8 bl = *(const short8*)(krow + kdiff + kc * 32);
        #pragma unroll
        for (int mt = 0; mt < 2; ++mt) {
          s[mt][nt] = mfma16(qfh[mt][kc], bh, s[mt][nt]);
          s[mt][nt] = mfma16(qfh[mt][kc], bl, s[mt][nt]);
          s[mt][nt] = mfma16(qfl[mt][kc], bh, s[mt][nt]);
        }
      }
    }

    // ---- scale + causal mask ----
    const bool dg = (kt >= 2 * qt);
    #pragma unroll
    for (int mt = 0; mt < 2; ++mt)
      #pragma unroll
      for (int nt = 0; nt < 4; ++nt)
        #pragma unroll
        for (int r = 0; r < 4; ++r) {
          float v = s[mt][nt][r] * ATT_SCALE;
          if (dg) {
            int kcol = t0 + nt * 16 + l16;
            int qrow = qbase + wvi * 32 + mt * 16 + quad * 4 + r;
            if (kcol > qrow) v = -1e30f;
          }
          s[mt][nt][r] = v;
        }

    // ---- online softmax ----
    float alf[2][4];
    #pragma unroll
    for (int mt = 0; mt < 2; ++mt)
      #pragma unroll
      for (int r = 0; r < 4; ++r) {
        float mx = fmaxf(fmaxf(s[mt][0][r], s[mt][1][r]), fmaxf(s[mt][2][r], s[mt][3][r]));
        mx = fmaxf(mx, __shfl_xor(mx, 1));
        mx = fmaxf(mx, __shfl_xor(mx, 2));
        mx = fmaxf(mx, __shfl_xor(mx, 4));
        mx = fmaxf(mx, __shfl_xor(mx, 8));
        float mnew = fmaxf(mrun[mt][r], mx);
        float al = expf(mrun[mt][r] - mnew);
        float ps = 0.f;
        #pragma unroll
        for (int nt = 0; nt < 4; ++nt) {
          float pv = expf(s[mt][nt][r] - mnew);
          s[mt][nt][r] = pv;
          ps += pv;
        }
        ps += __shfl_xor(ps, 1); ps += __shfl_xor(ps, 2);
        ps += __shfl_xor(ps, 4); ps += __shfl_xor(ps, 8);
        lrun[mt][r] = lrun[mt][r] * al + ps;
        mrun[mt][r] = mnew;
        alf[mt][r] = al;
      }
    #pragma unroll
    for (int mt = 0; mt < 2; ++mt)
      #pragma unroll
      for (int dt = 0; dt < 8; ++dt)
        #pragma unroll
        for (int r = 0; r < 4; ++r)
          oacc[mt][dt][r] *= alf[mt][r];

    // ---- P -> per-wave LDS (C-layout -> A-layout transpose), no barrier ----
    #pragma unroll
    for (int mt = 0; mt < 2; ++mt)
      #pragma unroll
      for (int nt = 0; nt < 4; ++nt)
        #pragma unroll
        for (int r = 0; r < 4; ++r) {
          int row = mt * 16 + quad * 4 + r;        // 0..31 (wave-local)
          int col = nt * 16 + l16;
          int idx = (row * 8 + ((col >> 3) ^ (row & 7))) * 8 + (col & 7);
          float pv = s[mt][nt][r];
          u16 hb = f2bf(pv);
          Ph[idx] = hb;
          Pl[idx] = f2bf(pv - bf2f(hb));
        }

    // ---- O += P V, V^T frags direct from global ----
    #pragma unroll
    for (int kc = 0; kc < 2; ++kc) {
      short8 ph[2], pl[2];
      #pragma unroll
      for (int mt = 0; mt < 2; ++mt) {
        int m = mt * 16 + l16;
        int idx = (m * 8 + ((kc * 4 + quad) ^ (m & 7))) * 8;
        ph[mt] = *(const short8*)&Ph[idx];
        pl[mt] = *(const short8*)&Pl[idx];
      }
      #pragma unroll
      for (int dt = 0; dt < 8; ++dt) {
        const u16* vrow = vh + (long)(kvh * HDIM + dt * 16 + l16) * TT
                             + t0 + kc * 32 + quad * 8;
        short8 wh = *(const short8*)vrow;
        short8 wl = *(const short8*)(vrow + vdiff);
        #pragma unroll
        for (int mt = 0; mt < 2; ++mt) {
          oacc[mt][dt] = mfma16(ph[mt], wh, oacc[mt][dt]);
          oacc[mt][dt] = mfma16(ph[mt], wl, oacc[mt][dt]);
          oacc[mt][dt] = mfma16(pl[mt], wh, oacc[mt][dt]);
        }
      }
    }
  }
  #pragma unroll
  for (int mt = 0; mt < 2; ++mt)
    #pragma unroll
    for (int dt = 0; dt < 8; ++dt)
      #pragma unroll
      for (int r = 0; r < 4; ++r) {
        int row = qbase + wvi * 32 + mt * 16 + quad * 4 + r;
        int d = dt * 16 + l16;
        float v = oacc[mt][dt][r] / lrun[mt][r];
        long ix = (long)row * (NHD * HDIM) + head * HDIM + d;
        u16 hb = f2bf(v);
        oh[ix] = hb;
        ol[ix] = f2bf(v - bf2f(hb));
      }
}

// ---------------- MoE routing (fp32, exact top-k semantics) ----------------
__global__ void routing_kernel(const float* __restrict__ t32, const float* __restrict__ gw,
                               const float* __restrict__ gb,
                               int* inds, float* wv, int* counts) {
  int t = blockIdx.x;
  int lane = threadIdx.x;
  const float* tr = t32 + (long)t * DM;
  float4v tv[8];
  #pragma unroll
  for (int j = 0; j < 8; ++j) tv[j] = *(const float4v*)(tr + lane * 32 + j * 4);
  float sc[16];
  for (int e = 0; e < 16; ++e) {
    const float* g = gw + (long)e * DM + lane * 32;
    float acc = 0.f;
    #pragma unroll
    for (int j = 0; j < 8; ++j) {
      float4v gv = *(const float4v*)(g + j * 4);
      acc += tv[j][0]*gv[0] + tv[j][1]*gv[1] + tv[j][2]*gv[2] + tv[j][3]*gv[3];
    }
    #pragma unroll
    for (int m = 1; m < 64; m <<= 1) acc += __shfl_xor(acc, m);
    sc[e] = 1.f / (1.f + expf(-acc));
  }
  if (lane == 0) {
    float s2[16];
    for (int e = 0; e < 16; ++e) s2[e] = sc[e] + gb[e];
    float gs[4];
    for (int g = 0; g < 4; ++g) {
      float xq[4] = { s2[4*g], s2[4*g+1], s2[4*g+2], s2[4*g+3] };
      int am = 0; float m1 = xq[0];
      for (int i = 1; i < 4; ++i) if (xq[i] > m1) { m1 = xq[i]; am = i; }
      float m2 = -1e30f;
      for (int i = 0; i < 4; ++i) if (i != am) m2 = fmaxf(m2, xq[i]);
      gs[g] = m1 + m2;
    }
    int g0 = 0;
    for (int g = 1; g < 4; ++g) if (gs[g] > gs[g0]) g0 = g;
    int g1 = -1;
    for (int g = 0; g < 4; ++g) if (g != g0 && (g1 < 0 || gs[g] > gs[g1])) g1 = g;
    float msk[16];
    for (int e = 0; e < 16; ++e) {
      int g = e >> 2;
      msk[e] = (g == g0 || g == g1) ? s2[e] : 0.0f;
    }
    int id[4]; float w[4]; float wsum = 0.f;
    for (int j = 0; j < 4; ++j) {
      int bi = 0; float bv = msk[0];
      for (int e = 1; e < 16; ++e) if (msk[e] > bv) { bv = msk[e]; bi = e; }
      id[j] = bi; w[j] = sc[bi]; msk[bi] = -1e30f;
      wsum += w[j];
    }
    float scale = 2.5f / (wsum + 1e-20f);
    for (int j = 0; j < 4; ++j) {
      inds[t * 4 + j] = id[j];
      wv[t * 4 + j] = w[j] * scale;
      atomicAdd(&counts[id[j]], 1);
    }
  }
}

__global__ void scan_kernel(int* ctrl) {   // ctrl: [0..15]=counts [16..31]=offs [32..47]=cursor
  if (threadIdx.x == 0) {
    int a = 0;
    for (int e = 0; e < 16; ++e) { ctrl[16 + e] = a; a += ctrl[e]; }
  }
}

__global__ void assign_kernel(const int* inds, const float* wv, int* ctrl,
                              int* perm, float* wslot, int* inv) {
  int t = blockIdx.x * 256 + threadIdx.x;
  if (t >= TT) return;
  for (int j = 0; j < 4; ++j) {
    int e = inds[t * 4 + j];
    int pos = atomicAdd(&ctrl[32 + e], 1);
    int s = ctrl[16 + e] + pos;
    perm[s] = t;
    wslot[s] = wv[t * 4 + j];
    inv[t * 4 + j] = s;
  }
}

__global__ void hm_moe_kernel(const u16* __restrict__ gu, const float* __restrict__ wslot,
                              u16* __restrict__ hm) {
  int slot = blockIdx.x;
  int i = threadIdx.x * 4;
  float w = wslot[slot];
  const u16* gp = gu + (long)slot * 2048;
  short4v gv = *(const short4v*)(gp + i);
  short4v uv = *(const short4v*)(gp + 1024 + i);
  short4v ov;
  #pragma unroll
  for (int c = 0; c < 4; ++c) {
    float g = bf2f((u16)gv[c]);
    float u = bf2f((u16)uv[c]);
    float h = g / (1.f + expf(-g)) * u * w;
    ov[c] = (short)f2bf(h);
  }
  *(short4v*)&hm[(long)slot * 1024 + i] = ov;
}

__global__ void hm_sh_kernel(const u16* __restrict__ gu, u16* __restrict__ hm) {
  int t = blockIdx.x;
  int i = threadIdx.x * 8;
  const u16* gp = gu + (long)t * 4096 + i;
  const u16* up = gu + (long)t * 4096 + 2048 + i;
  u16* op = hm + (long)t * 2048 + i;
  #pragma unroll
  for (int c = 0; c < 2; ++c) {
    short4v gv = *(const short4v*)(gp + c * 4);
    short4v uv = *(const short4v*)(up + c * 4);
    short4v ov;
    #pragma unroll
    for (int q = 0; q < 4; ++q) {
      float g = bf2f((u16)gv[q]);
      float u = bf2f((u16)uv[q]);
      float h = g / (1.f + expf(-g)) * u;
      ov[q] = (short)f2bf(h);
    }
    *(short4v*)(op + c * 4) = ov;
  }
}

// ---------------- launch ----------------
extern "C" void kernel_launch(void* const* d_in, const int* in_sizes, int n_in,
                              void* d_out, int out_size, void* d_ws, size_t ws_size,
                              hipStream_t stream) {
  (void)in_sizes; (void)n_in; (void)out_size; (void)ws_size;
  const float* x   = (const float*)d_in[0];
  const float* wq  = (const float*)d_in[1];
  const float* wk  = (const float*)d_in[2];
  const float* wvv = (const float*)d_in[3];
  const float* wo  = (const float*)d_in[4];
  const float* qnw = (const float*)d_in[5];
  const float* knw = (const float*)d_in[6];
  const float* ln1 = (const float*)d_in[7];
  const float* ln2 = (const float*)d_in[8];
  const float* gw  = (const float*)d_in[9];
  const float* gb  = (const float*)d_in[10];
  const float* wg  = (const float*)d_in[11];
  const float* wu  = (const float*)d_in[12];
  const float* wd  = (const float*)d_in[13];
  const float* shg = (const float*)d_in[14];
  const float* shu = (const float*)d_in[15];
  const float* shd = (const float*)d_in[16];
  float* out = (float*)d_out;

  char* wp = (char*)d_ws;
  auto alloc = [&](size_t b) -> char* { char* r = wp; wp += (b + 255) & ~(size_t)255; return r; };
  u16* h_hi   = (u16*)alloc((size_t)TT * DM * 2);
  u16* h_lo   = (u16*)alloc((size_t)TT * DM * 2);
  float* q_lin = (float*)alloc((size_t)TT * 2048 * 4);
  float* k_lin = (float*)alloc((size_t)TT * 512 * 4);
  u16* q_hi   = (u16*)alloc((size_t)TT * 2048 * 2);
  u16* q_lo   = (u16*)alloc((size_t)TT * 2048 * 2);
  u16* k_hi   = (u16*)alloc((size_t)TT * 512 * 2);
  u16* k_lo   = (u16*)alloc((size_t)TT * 512 * 2);
  u16* vT_hi  = (u16*)alloc((size_t)512 * TT * 2);
  u16* vT_lo  = (u16*)alloc((size_t)512 * TT * 2);
  u16* o_hi   = (u16*)alloc((size_t)TT * 2048 * 2);
  u16* o_lo   = (u16*)alloc((size_t)TT * 2048 * 2);
  float* h1   = (float*)alloc((size_t)TT * DM * 4);
  float* t32  = (float*)alloc((size_t)TT * DM * 4);
  u16* t_bf   = (u16*)alloc((size_t)TT * DM * 2);
  u16* gu_sh  = (u16*)alloc((size_t)TT * 4096 * 2);
  u16* hm_sh  = (u16*)alloc((size_t)TT * 2048 * 2);
  u16* gu_moe = (u16*)alloc((size_t)8192 * 2048 * 2);
  u16* hm_moe = (u16*)alloc((size_t)8192 * 1024 * 2);
  u16* dtmp   = (u16*)alloc((size_t)8192 * 2048 * 2);
  int* inds   = (int*)alloc((size_t)TT * 4 * 4);
  float* wvals = (float*)alloc((size_t)TT * 4 * 4);
  int* ctrl   = (int*)alloc(256);
  int* perm   = (int*)alloc(8192 * 4);
  float* wslot = (float*)alloc(8192 * 4);
  int* inv    = (int*)alloc((size_t)TT * 4 * 4);
  const int NQ = 2048 * 2048, NK = 512 * 2048;
  u16* wq_c  = (u16*)alloc((size_t)NQ * 2 * 2);
  u16* wk_c  = (u16*)alloc((size_t)NK * 2 * 2);
  u16* wv_c  = (u16*)alloc((size_t)NK * 2 * 2);
  u16* wo_c  = (u16*)alloc((size_t)NQ * 2 * 2);
  const int NGU = 16 * NI * DM;
  u16* wg_c  = (u16*)alloc((size_t)NGU * 2);
  u16* wu_c  = (u16*)alloc((size_t)NGU * 2);
  u16* wd_c  = (u16*)alloc((size_t)NGU * 2);
  u16* shg_c = (u16*)alloc((size_t)NQ * 2);
  u16* shu_c = (u16*)alloc((size_t)NQ * 2);
  u16* shd_c = (u16*)alloc((size_t)NQ * 2);

  hipMemsetAsync(ctrl, 0, 256, stream);

  // 0. weight conversion
  cvt_split<<<NQ / 4 / 256, 256, 0, stream>>>(wq, wq_c, wq_c + NQ, NQ);
  cvt_split<<<NK / 4 / 256, 256, 0, stream>>>(wk, wk_c, wk_c + NK, NK);
  cvt_split<<<NK / 4 / 256, 256, 0, stream>>>(wvv, wv_c, wv_c + NK, NK);
  cvt_split<<<NQ / 4 / 256, 256, 0, stream>>>(wo, wo_c, wo_c + NQ, NQ);
  cvt_plain<<<NGU / 8 / 256, 256, 0, stream>>>(wg, wg_c, NGU);
  cvt_plain<<<NGU / 8 / 256, 256, 0, stream>>>(wu, wu_c, NGU);
  cvt_plain<<<NGU / 8 / 256, 256, 0, stream>>>(wd, wd_c, NGU);
  cvt_plain<<<NQ / 8 / 256, 256, 0, stream>>>(shg, shg_c, NQ);
  cvt_plain<<<NQ / 8 / 256, 256, 0, stream>>>(shu, shu_c, NQ);
  cvt_plain<<<NQ / 8 / 256, 256, 0, stream>>>(shd, shd_c, NQ);

  // 1. h = rms(x, ln1) -> split bf16
  rms_kernel<<<TT, 256, 0, stream>>>(x, ln1, h_hi, h_lo, nullptr, nullptr);

  // 2. q_lin | k_lin = h @ [w_q; w_k]^T  (split, fp32-fidelity)
  { GemmP p{}; p.Ah = h_hi; p.aloOff = h_lo - h_hi;
    p.B0h = wq_c; p.blo0 = NQ; p.B1h = wk_c; p.blo1 = NK; p.ns0 = 2048;
    p.K = DM; p.fixedM = TT; p.maxRow = TT - 1;
    p.oF = q_lin; p.ldF = 2048; p.oF2 = k_lin; p.ldF2 = 512; p.osplit = 2048;
    gemm_bt<0, true><<<dim3(16, 20, 1), 256, 0, stream>>>(p); }

  // 3. vT = (h @ w_v^T)^T  (split planes, transposed for attention)
  { GemmP p{}; p.Ah = h_hi; p.aloOff = h_lo - h_hi;
    p.B0h = wv_c; p.blo0 = NK; p.B1h = wv_c; p.blo1 = NK; p.ns0 = 1 << 30;
    p.K = DM; p.fixedM = TT; p.maxRow = TT - 1;
    p.oB = vT_hi; p.oBlo = vT_lo - vT_hi; p.ldB = TT;
    gemm_bt<1, true><<<dim3(16, 4, 1), 256, 0, stream>>>(p); }

  // 4. per-head rms + rope (f64 angles) -> split bf16 q/k
  rope_kernel<<<TT * 20 / 4, 256, 0, stream>>>(q_lin, k_lin, qnw, knw, q_hi, q_lo, k_hi, k_lo);

  // 5. flash attention -> split bf16 o
  attn_kernel<<<dim3(NHD, 16, 1), 256, 0, stream>>>(q_hi, q_lo, k_hi, k_lo, vT_hi, vT_lo, o_hi, o_lo);

  // 6. h1 = x + o @ w_o^T  (split)
  { GemmP p{}; p.Ah = o_hi; p.aloOff = o_lo - o_hi;
    p.B0h = wo_c; p.blo0 = NQ; p.B1h = wo_c; p.blo1 = NQ; p.ns0 = 1 << 30;
    p.K = DM; p.fixedM = TT; p.maxRow = TT - 1;
    p.oF = h1; p.ldF = 2048; p.addX = x;
    gemm_bt<2, true><<<dim3(16, 16, 1), 256, 0, stream>>>(p); }

  // 7. t = rms(h1, ln2) -> f32 (routing) + bf16 (experts)
  rms_kernel<<<TT, 256, 0, stream>>>(h1, ln2, nullptr, nullptr, t32, t_bf);

  // 8. routing (fp32) + slot assignment
  routing_kernel<<<TT, 64, 0, stream>>>(t32, gw, gb, inds, wvals, ctrl);
  scan_kernel<<<1, 64, 0, stream>>>(ctrl);
  assign_kernel<<<8, 256, 0, stream>>>(inds, wvals, ctrl, perm, wslot, inv);

  // 9. shared expert: gu -> hm -> (down fused into final)
  { GemmP p{}; p.Ah = t_bf; p.B0h = shg_c; p.B1h = shu_c; p.ns0 = 2048; p.K = DM;
    p.fixedM = TT; p.maxRow = TT - 1; p.oB = gu_sh; p.ldB = 4096;
    gemm_bt<3, false><<<dim3(16, 32, 1), 256, 0, stream>>>(p); }
  hm_sh_kernel<<<TT, 256, 0, stream>>>(gu_sh, hm_sh);

  // 10. MoE: gathered g/u GEMM, silu*u*w, down GEMM -> per-slot dtmp
  { GemmP p{}; p.Ah = t_bf; p.permA = perm; p.cnt = ctrl; p.offs = ctrl + 16;
    p.fixedM = TT; p.maxRow = 8191;
    p.B0h = wg_c; p.B1h = wu_c; p.ns0 = 1024; p.bstride = (long)NI * DM; p.K = DM;
    p.oB = gu_moe; p.ldB = 2048;
    gemm_bt<3, false><<<dim3(16, 16, 16), 256, 0, stream>>>(p); }
  hm_moe_kernel<<<8192, 256, 0, stream>>>(gu_moe, wslot, hm_moe);
  { GemmP p{}; p.Ah = hm_moe; p.cnt = ctrl; p.offs = ctrl + 16;
    p.fixedM = TT; p.maxRow = 8191;
    p.B0h = wd_c; p.B1h = wd_c; p.ns0 = 1 << 30; p.bstride = (long)DM * NI; p.K = NI;
    p.oB = dtmp; p.ldB = 2048;
    gemm_bt<3, false><<<dim3(16, 16, 16), 256, 0, stream>>>(p); }

  // 11. out = h1 + Σ dtmp[slots(t)] + hm_sh @ sh_d^T
  { GemmP p{}; p.Ah = hm_sh; p.B0h = shd_c; p.B1h = shd_c; p.ns0 = 1 << 30; p.K = DM;
    p.fixedM = TT; p.maxRow = TT - 1;
    p.oF = out; p.ldF = 2048; p.addX = h1; p.dslots = dtmp; p.inv = inv;
    gemm_bt<5, false><<<dim3(16, 16, 1), 256, 0, stream>>>(p); }
}

// Round 4
// 1549.080 us; speedup vs baseline: 1.2461x; 1.2461x over previous
//
#include <hip/hip_runtime.h>
#include <math.h>

#define TT 2048
#define DM 2048
#define NHD 16
#define NKV 4
#define HDIM 128
#define NI 1024
#define ATT_SCALE 0.08838834764831845f

typedef unsigned short u16;
typedef __attribute__((ext_vector_type(8))) short short8;
typedef __attribute__((ext_vector_type(4))) short short4v;
typedef __attribute__((ext_vector_type(4))) float float4v;

#define AS1 __attribute__((address_space(1)))
#define AS3 __attribute__((address_space(3)))

__device__ __forceinline__ u16 f2bf(float f) {
  union { float f; unsigned u; } v; v.f = f;
  unsigned r = v.u + 0x7fffu + ((v.u >> 16) & 1u);
  return (u16)(r >> 16);
}
__device__ __forceinline__ float bf2f(u16 h) {
  union { unsigned u; float f; } v; v.u = ((unsigned)h) << 16;
  return v.f;
}
__device__ __forceinline__ float4v mfma16(short8 a, short8 b, float4v c) {
  return __builtin_amdgcn_mfma_f32_16x16x32_bf16(a, b, c, 0, 0, 0);
}
__device__ __forceinline__ void gl_lds(const u16* g, u16* l) {
  __builtin_amdgcn_global_load_lds((const AS1 void*)g, (AS3 void*)l, 16, 0, 0);
}

// ---------------- weight conversion ----------------
__global__ void cvt_split(const float* __restrict__ s, u16* __restrict__ oh,
                          u16* __restrict__ ol, int n) {
  int i = (blockIdx.x * 256 + threadIdx.x) * 4;
  if (i >= n) return;
  float4v v = *(const float4v*)(s + i);
  short4v vh, vl;
  #pragma unroll
  for (int c = 0; c < 4; ++c) {
    u16 hb = f2bf(v[c]);
    vh[c] = (short)hb;
    vl[c] = (short)f2bf(v[c] - bf2f(hb));
  }
  *(short4v*)(oh + i) = vh;
  *(short4v*)(ol + i) = vl;
}

__global__ void cvt_plain(const float* __restrict__ s, u16* __restrict__ o, int n) {
  int i = (blockIdx.x * 256 + threadIdx.x) * 8;
  if (i >= n) return;
  float4v v0 = *(const float4v*)(s + i);
  float4v v1 = *(const float4v*)(s + i + 4);
  short8 ov;
  #pragma unroll
  for (int c = 0; c < 4; ++c) {
    ov[c] = (short)f2bf(v0[c]);
    ov[c + 4] = (short)f2bf(v1[c]);
  }
  *(short8*)(o + i) = ov;
}

// ---------------- RMSNorm (row = 2048) ----------------
__global__ void rms_kernel(const float* __restrict__ in, const float* __restrict__ w,
                           u16* oh, u16* ol, float* of, u16* ob) {
  const int row = blockIdx.x, tid = threadIdx.x;
  const int lane = tid & 63, wvi = tid >> 6;
  const float* xr = in + (long)row * DM;
  float4v a = *(const float4v*)(xr + tid * 4);
  float4v b = *(const float4v*)(xr + 1024 + tid * 4);
  float ss = a[0]*a[0] + a[1]*a[1] + a[2]*a[2] + a[3]*a[3]
           + b[0]*b[0] + b[1]*b[1] + b[2]*b[2] + b[3]*b[3];
  #pragma unroll
  for (int m = 1; m < 64; m <<= 1) ss += __shfl_xor(ss, m);
  __shared__ float red[4];
  if (lane == 0) red[wvi] = ss;
  __syncthreads();
  float tot = red[0] + red[1] + red[2] + red[3];
  float sc = 1.0f / sqrtf(tot * (1.0f / 2048.0f) + 1e-5f);
  float4v w0 = *(const float4v*)(w + tid * 4);
  float4v w1 = *(const float4v*)(w + 1024 + tid * 4);
  #pragma unroll
  for (int c = 0; c < 4; ++c) {
    float v0 = a[c] * sc * w0[c];
    float v1 = b[c] * sc * w1[c];
    long i0 = (long)row * DM + tid * 4 + c;
    long i1 = i0 + 1024;
    if (oh) {
      u16 h0 = f2bf(v0); oh[i0] = h0; ol[i0] = f2bf(v0 - bf2f(h0));
      u16 h1 = f2bf(v1); oh[i1] = h1; ol[i1] = f2bf(v1 - bf2f(h1));
    }
    if (of) { of[i0] = v0; of[i1] = v1; }
    if (ob) { ob[i0] = f2bf(v0); ob[i1] = f2bf(v1); }
  }
}

// ---------------- per-head RMSNorm + RoPE ----------------
__global__ void rope_kernel(const float* __restrict__ qlin, const float* __restrict__ klin,
                            const float* __restrict__ qw, const float* __restrict__ kw,
                            u16* qh, u16* ql, u16* kh, u16* kl) {
  int rw = blockIdx.x * 4 + (threadIdx.x >> 6);
  int lane = threadIdx.x & 63;
  int t = rw / 20, hh = rw - t * 20;
  const float* src; const float* nw; u16 *dh, *dl;
  if (hh < 16) {
    long ofs = (long)t * 2048 + hh * 128;
    src = qlin + ofs; nw = qw; dh = qh + ofs; dl = ql + ofs;
  } else {
    long ofs = (long)t * 512 + (hh - 16) * 128;
    src = klin + ofs; nw = kw; dh = kh + ofs; dl = kl + ofs;
  }
  float x1 = src[lane], x2 = src[lane + 64];
  float ss = x1 * x1 + x2 * x2;
  #pragma unroll
  for (int m = 1; m < 64; m <<= 1) ss += __shfl_xor(ss, m);
  float sc = 1.0f / sqrtf(ss * (1.0f / 128.0f) + 1e-5f);
  x1 *= sc * nw[lane];
  x2 *= sc * nw[lane + 64];
  double inv = pow(1.0e6, -(double)lane * (1.0 / 64.0));
  double ang = (double)t * inv;
  float cs = (float)cos(ang), sn = (float)sin(ang);
  float o1 = x1 * cs - x2 * sn;
  float o2 = x2 * cs + x1 * sn;
  u16 hb1 = f2bf(o1); dh[lane] = hb1;      dl[lane] = f2bf(o1 - bf2f(hb1));
  u16 hb2 = f2bf(o2); dh[lane + 64] = hb2; dl[lane + 64] = f2bf(o2 - bf2f(hb2));
}

// ---------------- GEMM: C[M,N] = A[M,K] * B[N,K]^T ----------------
struct GemmP {
  const u16* Ah; long aloOff;
  const u16* B0h; const u16* B1h; long blo0; long blo1; long bstride; int ns0;
  int K;
  const int* permA; const int* cnt; const int* offs;
  int fixedM; int maxRow;
  float* oF; int ldF;
  float* oF2; int ldF2; int osplit;
  u16* oB; long oBlo; int ldB;
  const float* addX;
  const u16* dslots; const int* inv;
};

template<int EPI, bool SPLIT>
__launch_bounds__(256, 2)
__global__ void gemm_bt(GemmP p) {
  const int e = blockIdx.z;
  const int cnt = p.cnt ? p.cnt[e] : p.fixedM;
  const int mt0 = blockIdx.x * 128;
  if (mt0 >= cnt) return;
  const int off = p.offs ? p.offs[e] : 0;
  const int nt0 = blockIdx.y * 128;

  __shared__ u16 lAh[128 * 64];
  __shared__ u16 lBh[128 * 64];
  __shared__ u16 lAl[SPLIT ? 128 * 64 : 8];
  __shared__ u16 lBl[SPLIT ? 128 * 64 : 8];

  const int tid = threadIdx.x;
  const int lane = tid & 63, wvi = tid >> 6;
  const int quad = lane >> 4, l16 = lane & 15;
  const int wm = (wvi >> 1) * 64, wn = (wvi & 1) * 64;
  const int srow = tid >> 3;                 // 0..31
  const int scc = (tid & 7) ^ (srow & 7);    // logical chunk for staging

  const u16* agp[4];
  #pragma unroll
  for (int i = 0; i < 4; ++i) {
    int m = mt0 + i * 32 + srow;
    int r = off + m; if (r > p.maxRow) r = p.maxRow;
    if (p.permA) r = p.permA[r];
    agp[i] = p.Ah + (long)r * p.K + scc * 8;
  }
  const u16* bgph[4]; const u16* bgpl[4];
  #pragma unroll
  for (int j = 0; j < 4; ++j) {
    int n = nt0 + j * 32 + srow;
    const u16* bp; long lo;
    if (n < p.ns0) { bp = p.B0h + (long)e * p.bstride + (long)n * p.K; lo = p.blo0; }
    else           { bp = p.B1h + (long)e * p.bstride + (long)(n - p.ns0) * p.K; lo = p.blo1; }
    bgph[j] = bp + scc * 8;
    bgpl[j] = bp + lo + scc * 8;
  }

  float4v acc[4][4];
  #pragma unroll
  for (int a = 0; a < 4; ++a)
    #pragma unroll
    for (int b = 0; b < 4; ++b)
      acc[a][b] = (float4v){0.f, 0.f, 0.f, 0.f};

  const int wofs = wvi * 64 * 8;

  for (int k0 = 0; k0 < p.K; k0 += 64) {
    __syncthreads();
    #pragma unroll
    for (int i = 0; i < 4; ++i) {
      gl_lds(agp[i] + k0, &lAh[i * 2048 + wofs]);
      if constexpr (SPLIT) gl_lds(agp[i] + p.aloOff + k0, &lAl[i * 2048 + wofs]);
    }
    #pragma unroll
    for (int j = 0; j < 4; ++j) {
      gl_lds(bgph[j] + k0, &lBh[j * 2048 + wofs]);
      if constexpr (SPLIT) gl_lds(bgpl[j] + k0, &lBl[j * 2048 + wofs]);
    }
    __syncthreads();
    #pragma unroll
    for (int kc = 0; kc < 2; ++kc) {
      short8 ah[4], al[4], bh[4], bl[4];
      #pragma unroll
      for (int t = 0; t < 4; ++t) {
        int m = wm + t * 16 + l16;
        int ia = (m * 8 + ((kc * 4 + quad) ^ (m & 7))) * 8;
        ah[t] = *(const short8*)&lAh[ia];
        if constexpr (SPLIT) al[t] = *(const short8*)&lAl[ia];
        int n = wn + t * 16 + l16;
        int ib = (n * 8 + ((kc * 4 + quad) ^ (n & 7))) * 8;
        bh[t] = *(const short8*)&lBh[ib];
        if constexpr (SPLIT) bl[t] = *(const short8*)&lBl[ib];
      }
      #pragma unroll
      for (int mt = 0; mt < 4; ++mt)
        #pragma unroll
        for (int nt = 0; nt < 4; ++nt) {
          acc[mt][nt] = mfma16(ah[mt], bh[nt], acc[mt][nt]);
          if constexpr (SPLIT) {
            acc[mt][nt] = mfma16(ah[mt], bl[nt], acc[mt][nt]);
            acc[mt][nt] = mfma16(al[mt], bh[nt], acc[mt][nt]);
          }
        }
    }
  }

  #pragma unroll
  for (int mt = 0; mt < 4; ++mt) {
    #pragma unroll
    for (int nt = 0; nt < 4; ++nt) {
      const int n = nt0 + wn + nt * 16 + l16;
      const int mlb = wm + mt * 16 + quad * 4;
      if constexpr (EPI == 1) {            // transposed bf16 split store (vT)
        short4v vh, vl;
        #pragma unroll
        for (int r = 0; r < 4; ++r) {
          float v = acc[mt][nt][r];
          u16 hb = f2bf(v);
          vh[r] = (short)hb;
          vl[r] = (short)f2bf(v - bf2f(hb));
        }
        long ix = (long)n * p.ldB + (mt0 + mlb);
        *(short4v*)&p.oB[ix] = vh;
        *(short4v*)&p.oB[ix + p.oBlo] = vl;
      } else {
        #pragma unroll
        for (int r = 0; r < 4; ++r) {
          const int gm = mt0 + mlb + r;
          if (gm >= cnt) continue;
          float v = acc[mt][nt][r];
          if constexpr (EPI == 0) {        // f32, two-way column-split output
            if (n < p.osplit) p.oF[(long)gm * p.ldF + n] = v;
            else p.oF2[(long)gm * p.ldF2 + (n - p.osplit)] = v;
          } else if constexpr (EPI == 2) { // + residual x -> f32
            long ix = (long)gm * p.ldF + n;
            p.oF[ix] = v + p.addX[ix];
          } else if constexpr (EPI == 3) { // bf16 (rows offset by expert base)
            p.oB[(long)(off + gm) * p.ldB + n] = f2bf(v);
          } else if constexpr (EPI == 5) { // final: + h1 + 4-slot MoE gather
            long ix = (long)gm * p.ldF + n;
            const int* iv = p.inv + gm * 4;
            float s = bf2f(p.dslots[(long)iv[0] * DM + n])
                    + bf2f(p.dslots[(long)iv[1] * DM + n])
                    + bf2f(p.dslots[(long)iv[2] * DM + n])
                    + bf2f(p.dslots[(long)iv[3] * DM + n]);
            p.oF[ix] = v + p.addX[ix] + s;
          }
        }
      }
    }
  }
}

// ---------------- flash attention (causal, GQA 4:1, split-bf16) ----------------
// 64-row q-tiles (wave = 16 rows), LDS-staged K/V (global_load_lds, 2 barriers
// per 64-token step), per-wave private P transpose. 512 blocks -> 2/CU.
__launch_bounds__(256, 2)
__global__ void attn_kernel(const u16* __restrict__ qh, const u16* __restrict__ ql,
                            const u16* __restrict__ kh, const u16* __restrict__ kl,
                            const u16* __restrict__ vh, const u16* __restrict__ vl,
                            u16* __restrict__ oh, u16* __restrict__ ol) {
  const int head = blockIdx.x;
  const int qt = 31 - (int)blockIdx.y;      // long blocks first
  const int kvh = head >> 2;
  const int tid = threadIdx.x;
  const int lane = tid & 63, wvi = tid >> 6;
  const int quad = lane >> 4, l16 = lane & 15;

  __shared__ u16 lKh[64 * 128];   // [ktok 64][d 128] swizzled
  __shared__ u16 lKl[64 * 128];
  __shared__ u16 lVh[128 * 64];   // [d 128][ktok 64] swizzled
  __shared__ u16 lVl[128 * 64];
  __shared__ u16 lP[4][2][16 * 64];   // per-wave private P hi/lo
  u16* Ph = &lP[wvi][0][0];
  u16* Pl = &lP[wvi][1][0];

  const int qbase = qt * 64;
  const int qrow0 = qbase + wvi * 16;
  short8 qfh[4], qfl[4];
  {
    int row = qrow0 + l16;
    const u16* ph = qh + (long)row * (NHD * HDIM) + head * HDIM + quad * 8;
    const u16* pl = ql + (long)row * (NHD * HDIM) + head * HDIM + quad * 8;
    #pragma unroll
    for (int kc = 0; kc < 4; ++kc) {
      qfh[kc] = *(const short8*)(ph + kc * 32);
      qfl[kc] = *(const short8*)(pl + kc * 32);
    }
  }
  float4v oacc[8];
  #pragma unroll
  for (int dt = 0; dt < 8; ++dt) oacc[dt] = (float4v){0.f, 0.f, 0.f, 0.f};
  float mrun[4], lrun[4];
  #pragma unroll
  for (int r = 0; r < 4; ++r) { mrun[r] = -INFINITY; lrun[r] = 0.f; }

  const int sck = (tid & 15) ^ (tid >> 4);            // K tile (16 chunks/row)
  const int scv = (tid & 7) ^ ((tid >> 3) & 7);       // V tile (8 chunks/row)
  const int nsteps = qt + 1;

  for (int kt = 0; kt < nsteps; ++kt) {
    const int t0 = kt * 64;
    __syncthreads();                 // all waves done reading prev K/V
    #pragma unroll
    for (int i = 0; i < 4; ++i) {
      int krow = i * 16 + (tid >> 4);
      long kg = (long)(t0 + krow) * (NKV * HDIM) + kvh * HDIM + sck * 8;
      gl_lds(kh + kg, &lKh[(i * 256 + wvi * 64) * 8]);
      gl_lds(kl + kg, &lKl[(i * 256 + wvi * 64) * 8]);
      int vrow = i * 32 + (tid >> 3);
      long vg = (long)(kvh * HDIM + vrow) * TT + t0 + scv * 8;
      gl_lds(vh + vg, &lVh[(i * 256 + wvi * 64) * 8]);
      gl_lds(vl + vg, &lVl[(i * 256 + wvi * 64) * 8]);
    }
    __syncthreads();                 // staging complete

    // ---- S = Q K^T (split 3-product) ----
    float4v s[4];
    #pragma unroll
    for (int nt = 0; nt < 4; ++nt) s[nt] = (float4v){0.f, 0.f, 0.f, 0.f};
    #pragma unroll
    for (int kc = 0; kc < 4; ++kc) {
      #pragma unroll
      for (int nt = 0; nt < 4; ++nt) {
        int n = nt * 16 + l16;
        int idx = (n * 16 + ((kc * 4 + quad) ^ (n & 15))) * 8;
        short8 bh = *(const short8*)&lKh[idx];
        short8 bl = *(const short8*)&lKl[idx];
        s[nt] = mfma16(qfh[kc], bh, s[nt]);
        s[nt] = mfma16(qfh[kc], bl, s[nt]);
        s[nt] = mfma16(qfl[kc], bh, s[nt]);
      }
    }

    // ---- scale + causal mask (diagonal step only) ----
    const bool dg = (kt == qt);
    #pragma unroll
    for (int nt = 0; nt < 4; ++nt)
      #pragma unroll
      for (int r = 0; r < 4; ++r) {
        float v = s[nt][r] * ATT_SCALE;
        if (dg) {
          int kcol = t0 + nt * 16 + l16;
          int qrow = qrow0 + quad * 4 + r;
          if (kcol > qrow) v = -1e30f;
        }
        s[nt][r] = v;
      }

    // ---- online softmax ----
    float alf[4];
    #pragma unroll
    for (int r = 0; r < 4; ++r) {
      float mx = fmaxf(fmaxf(s[0][r], s[1][r]), fmaxf(s[2][r], s[3][r]));
      mx = fmaxf(mx, __shfl_xor(mx, 1));
      mx = fmaxf(mx, __shfl_xor(mx, 2));
      mx = fmaxf(mx, __shfl_xor(mx, 4));
      mx = fmaxf(mx, __shfl_xor(mx, 8));
      float mnew = fmaxf(mrun[r], mx);
      float al = expf(mrun[r] - mnew);
      float ps = 0.f;
      #pragma unroll
      for (int nt = 0; nt < 4; ++nt) {
        float pv = expf(s[nt][r] - mnew);
        s[nt][r] = pv;
        ps += pv;
      }
      ps += __shfl_xor(ps, 1); ps += __shfl_xor(ps, 2);
      ps += __shfl_xor(ps, 4); ps += __shfl_xor(ps, 8);
      lrun[r] = lrun[r] * al + ps;
      mrun[r] = mnew;
      alf[r] = al;
    }
    #pragma unroll
    for (int dt = 0; dt < 8; ++dt)
      #pragma unroll
      for (int r = 0; r < 4; ++r)
        oacc[dt][r] *= alf[r];

    // ---- P -> per-wave LDS (C->A layout), no barrier ----
    #pragma unroll
    for (int nt = 0; nt < 4; ++nt)
      #pragma unroll
      for (int r = 0; r < 4; ++r) {
        int row = quad * 4 + r;                  // 0..15 wave-local
        int col = nt * 16 + l16;
        int idx = (row * 8 + ((col >> 3) ^ (row & 7))) * 8 + (col & 7);
        float pv = s[nt][r];
        u16 hb = f2bf(pv);
        Ph[idx] = hb;
        Pl[idx] = f2bf(pv - bf2f(hb));
      }

    // ---- O += P V ----
    #pragma unroll
    for (int kc = 0; kc < 2; ++kc) {
      int idxp = (l16 * 8 + ((kc * 4 + quad) ^ (l16 & 7))) * 8;
      short8 ph = *(const short8*)&Ph[idxp];
      short8 pl = *(const short8*)&Pl[idxp];
      #pragma unroll
      for (int dt = 0; dt < 8; ++dt) {
        int d = dt * 16 + l16;
        int idx = (d * 8 + ((kc * 4 + quad) ^ (d & 7))) * 8;
        short8 wh = *(const short8*)&lVh[idx];
        short8 wl = *(const short8*)&lVl[idx];
        oacc[dt] = mfma16(ph, wh, oacc[dt]);
        oacc[dt] = mfma16(ph, wl, oacc[dt]);
        oacc[dt] = mfma16(pl, wh, oacc[dt]);
      }
    }
  }

  #pragma unroll
  for (int dt = 0; dt < 8; ++dt)
    #pragma unroll
    for (int r = 0; r < 4; ++r) {
      int row = qrow0 + quad * 4 + r;
      int d = dt * 16 + l16;
      float v = oacc[dt][r] / lrun[r];
      long ix = (long)row * (NHD * HDIM) + head * HDIM + d;
      u16 hb = f2bf(v);
      oh[ix] = hb;
      ol[ix] = f2bf(v - bf2f(hb));
    }
}

// ---------------- MoE routing (fp32, exact top-k semantics) ----------------
__global__ void routing_kernel(const float* __restrict__ t32, const float* __restrict__ gw,
                               const float* __restrict__ gb,
                               int* inds, float* wv, int* counts) {
  int t = blockIdx.x;
  int lane = threadIdx.x;
  const float* tr = t32 + (long)t * DM;
  float4v tv[8];
  #pragma unroll
  for (int j = 0; j < 8; ++j) tv[j] = *(const float4v*)(tr + lane * 32 + j * 4);
  float sc[16];
  for (int e = 0; e < 16; ++e) {
    const float* g = gw + (long)e * DM + lane * 32;
    float acc = 0.f;
    #pragma unroll
    for (int j = 0; j < 8; ++j) {
      float4v gv = *(const float4v*)(g + j * 4);
      acc += tv[j][0]*gv[0] + tv[j][1]*gv[1] + tv[j][2]*gv[2] + tv[j][3]*gv[3];
    }
    #pragma unroll
    for (int m = 1; m < 64; m <<= 1) acc += __shfl_xor(acc, m);
    sc[e] = 1.f / (1.f + expf(-acc));
  }
  if (lane == 0) {
    float s2[16];
    for (int e = 0; e < 16; ++e) s2[e] = sc[e] + gb[e];
    float gs[4];
    for (int g = 0; g < 4; ++g) {
      float xq[4] = { s2[4*g], s2[4*g+1], s2[4*g+2], s2[4*g+3] };
      int am = 0; float m1 = xq[0];
      for (int i = 1; i < 4; ++i) if (xq[i] > m1) { m1 = xq[i]; am = i; }
      float m2 = -1e30f;
      for (int i = 0; i < 4; ++i) if (i != am) m2 = fmaxf(m2, xq[i]);
      gs[g] = m1 + m2;
    }
    int g0 = 0;
    for (int g = 1; g < 4; ++g) if (gs[g] > gs[g0]) g0 = g;
    int g1 = -1;
    for (int g = 0; g < 4; ++g) if (g != g0 && (g1 < 0 || gs[g] > gs[g1])) g1 = g;
    float msk[16];
    for (int e = 0; e < 16; ++e) {
      int g = e >> 2;
      msk[e] = (g == g0 || g == g1) ? s2[e] : 0.0f;
    }
    int id[4]; float w[4]; float wsum = 0.f;
    for (int j = 0; j < 4; ++j) {
      int bi = 0; float bv = msk[0];
      for (int e = 1; e < 16; ++e) if (msk[e] > bv) { bv = msk[e]; bi = e; }
      id[j] = bi; w[j] = sc[bi]; msk[bi] = -1e30f;
      wsum += w[j];
    }
    float scale = 2.5f / (wsum + 1e-20f);
    for (int j = 0; j < 4; ++j) {
      inds[t * 4 + j] = id[j];
      wv[t * 4 + j] = w[j] * scale;
      atomicAdd(&counts[id[j]], 1);
    }
  }
}

__global__ void scan_kernel(int* ctrl) {   // ctrl: [0..15]=counts [16..31]=offs [32..47]=cursor
  if (threadIdx.x == 0) {
    int a = 0;
    for (int e = 0; e < 16; ++e) { ctrl[16 + e] = a; a += ctrl[e]; }
  }
}

__global__ void assign_kernel(const int* inds, const float* wv, int* ctrl,
                              int* perm, float* wslot, int* inv) {
  int t = blockIdx.x * 256 + threadIdx.x;
  if (t >= TT) return;
  for (int j = 0; j < 4; ++j) {
    int e = inds[t * 4 + j];
    int pos = atomicAdd(&ctrl[32 + e], 1);
    int s = ctrl[16 + e] + pos;
    perm[s] = t;
    wslot[s] = wv[t * 4 + j];
    inv[t * 4 + j] = s;
  }
}

__global__ void hm_moe_kernel(const u16* __restrict__ gu, const float* __restrict__ wslot,
                              u16* __restrict__ hm) {
  int slot = blockIdx.x;
  int i = threadIdx.x * 4;
  float w = wslot[slot];
  const u16* gp = gu + (long)slot * 2048;
  short4v gv = *(const short4v*)(gp + i);
  short4v uv = *(const short4v*)(gp + 1024 + i);
  short4v ov;
  #pragma unroll
  for (int c = 0; c < 4; ++c) {
    float g = bf2f((u16)gv[c]);
    float u = bf2f((u16)uv[c]);
    float h = g / (1.f + expf(-g)) * u * w;
    ov[c] = (short)f2bf(h);
  }
  *(short4v*)&hm[(long)slot * 1024 + i] = ov;
}

__global__ void hm_sh_kernel(const u16* __restrict__ gu, u16* __restrict__ hm) {
  int t = blockIdx.x;
  int i = threadIdx.x * 8;
  const u16* gp = gu + (long)t * 4096 + i;
  const u16* up = gu + (long)t * 4096 + 2048 + i;
  u16* op = hm + (long)t * 2048 + i;
  #pragma unroll
  for (int c = 0; c < 2; ++c) {
    short4v gv = *(const short4v*)(gp + c * 4);
    short4v uv = *(const short4v*)(up + c * 4);
    short4v ov;
    #pragma unroll
    for (int q = 0; q < 4; ++q) {
      float g = bf2f((u16)gv[q]);
      float u = bf2f((u16)uv[q]);
      float h = g / (1.f + expf(-g)) * u;
      ov[q] = (short)f2bf(h);
    }
    *(short4v*)(op + c * 4) = ov;
  }
}

// ---------------- launch ----------------
extern "C" void kernel_launch(void* const* d_in, const int* in_sizes, int n_in,
                              void* d_out, int out_size, void* d_ws, size_t ws_size,
                              hipStream_t stream) {
  (void)in_sizes; (void)n_in; (void)out_size; (void)ws_size;
  const float* x   = (const float*)d_in[0];
  const float* wq  = (const float*)d_in[1];
  const float* wk  = (const float*)d_in[2];
  const float* wvv = (const float*)d_in[3];
  const float* wo  = (const float*)d_in[4];
  const float* qnw = (const float*)d_in[5];
  const float* knw = (const float*)d_in[6];
  const float* ln1 = (const float*)d_in[7];
  const float* ln2 = (const float*)d_in[8];
  const float* gw  = (const float*)d_in[9];
  const float* gb  = (const float*)d_in[10];
  const float* wg  = (const float*)d_in[11];
  const float* wu  = (const float*)d_in[12];
  const float* wd  = (const float*)d_in[13];
  const float* shg = (const float*)d_in[14];
  const float* shu = (const float*)d_in[15];
  const float* shd = (const float*)d_in[16];
  float* out = (float*)d_out;

  char* wp = (char*)d_ws;
  auto alloc = [&](size_t b) -> char* { char* r = wp; wp += (b + 255) & ~(size_t)255; return r; };
  u16* h_hi   = (u16*)alloc((size_t)TT * DM * 2);
  u16* h_lo   = (u16*)alloc((size_t)TT * DM * 2);
  float* q_lin = (float*)alloc((size_t)TT * 2048 * 4);
  float* k_lin = (float*)alloc((size_t)TT * 512 * 4);
  u16* q_hi   = (u16*)alloc((size_t)TT * 2048 * 2);
  u16* q_lo   = (u16*)alloc((size_t)TT * 2048 * 2);
  u16* k_hi   = (u16*)alloc((size_t)TT * 512 * 2);
  u16* k_lo   = (u16*)alloc((size_t)TT * 512 * 2);
  u16* vT_hi  = (u16*)alloc((size_t)512 * TT * 2);
  u16* vT_lo  = (u16*)alloc((size_t)512 * TT * 2);
  u16* o_hi   = (u16*)alloc((size_t)TT * 2048 * 2);
  u16* o_lo   = (u16*)alloc((size_t)TT * 2048 * 2);
  float* h1   = (float*)alloc((size_t)TT * DM * 4);
  float* t32  = (float*)alloc((size_t)TT * DM * 4);
  u16* t_bf   = (u16*)alloc((size_t)TT * DM * 2);
  u16* gu_sh  = (u16*)alloc((size_t)TT * 4096 * 2);
  u16* hm_sh  = (u16*)alloc((size_t)TT * 2048 * 2);
  u16* gu_moe = (u16*)alloc((size_t)8192 * 2048 * 2);
  u16* hm_moe = (u16*)alloc((size_t)8192 * 1024 * 2);
  u16* dtmp   = (u16*)alloc((size_t)8192 * 2048 * 2);
  int* inds   = (int*)alloc((size_t)TT * 4 * 4);
  float* wvals = (float*)alloc((size_t)TT * 4 * 4);
  int* ctrl   = (int*)alloc(256);
  int* perm   = (int*)alloc(8192 * 4);
  float* wslot = (float*)alloc(8192 * 4);
  int* inv    = (int*)alloc((size_t)TT * 4 * 4);
  const int NQ = 2048 * 2048, NK = 512 * 2048;
  u16* wq_c  = (u16*)alloc((size_t)NQ * 2 * 2);
  u16* wk_c  = (u16*)alloc((size_t)NK * 2 * 2);
  u16* wv_c  = (u16*)alloc((size_t)NK * 2 * 2);
  u16* wo_c  = (u16*)alloc((size_t)NQ * 2 * 2);
  const int NGU = 16 * NI * DM;
  u16* wg_c  = (u16*)alloc((size_t)NGU * 2);
  u16* wu_c  = (u16*)alloc((size_t)NGU * 2);
  u16* wd_c  = (u16*)alloc((size_t)NGU * 2);
  u16* shg_c = (u16*)alloc((size_t)NQ * 2);
  u16* shu_c = (u16*)alloc((size_t)NQ * 2);
  u16* shd_c = (u16*)alloc((size_t)NQ * 2);

  hipMemsetAsync(ctrl, 0, 256, stream);

  // 0. weight conversion
  cvt_split<<<NQ / 4 / 256, 256, 0, stream>>>(wq, wq_c, wq_c + NQ, NQ);
  cvt_split<<<NK / 4 / 256, 256, 0, stream>>>(wk, wk_c, wk_c + NK, NK);
  cvt_split<<<NK / 4 / 256, 256, 0, stream>>>(wvv, wv_c, wv_c + NK, NK);
  cvt_split<<<NQ / 4 / 256, 256, 0, stream>>>(wo, wo_c, wo_c + NQ, NQ);
  cvt_plain<<<NGU / 8 / 256, 256, 0, stream>>>(wg, wg_c, NGU);
  cvt_plain<<<NGU / 8 / 256, 256, 0, stream>>>(wu, wu_c, NGU);
  cvt_plain<<<NGU / 8 / 256, 256, 0, stream>>>(wd, wd_c, NGU);
  cvt_plain<<<NQ / 8 / 256, 256, 0, stream>>>(shg, shg_c, NQ);
  cvt_plain<<<NQ / 8 / 256, 256, 0, stream>>>(shu, shu_c, NQ);
  cvt_plain<<<NQ / 8 / 256, 256, 0, stream>>>(shd, shd_c, NQ);

  // 1. h = rms(x, ln1) -> split bf16
  rms_kernel<<<TT, 256, 0, stream>>>(x, ln1, h_hi, h_lo, nullptr, nullptr);

  // 2. q_lin | k_lin = h @ [w_q; w_k]^T  (split, fp32-fidelity)
  { GemmP p{}; p.Ah = h_hi; p.aloOff = h_lo - h_hi;
    p.B0h = wq_c; p.blo0 = NQ; p.B1h = wk_c; p.blo1 = NK; p.ns0 = 2048;
    p.K = DM; p.fixedM = TT; p.maxRow = TT - 1;
    p.oF = q_lin; p.ldF = 2048; p.oF2 = k_lin; p.ldF2 = 512; p.osplit = 2048;
    gemm_bt<0, true><<<dim3(16, 20, 1), 256, 0, stream>>>(p); }

  // 3. vT = (h @ w_v^T)^T  (split planes, transposed for attention)
  { GemmP p{}; p.Ah = h_hi; p.aloOff = h_lo - h_hi;
    p.B0h = wv_c; p.blo0 = NK; p.B1h = wv_c; p.blo1 = NK; p.ns0 = 1 << 30;
    p.K = DM; p.fixedM = TT; p.maxRow = TT - 1;
    p.oB = vT_hi; p.oBlo = vT_lo - vT_hi; p.ldB = TT;
    gemm_bt<1, true><<<dim3(16, 4, 1), 256, 0, stream>>>(p); }

  // 4. per-head rms + rope (f64 angles) -> split bf16 q/k
  rope_kernel<<<TT * 20 / 4, 256, 0, stream>>>(q_lin, k_lin, qnw, knw, q_hi, q_lo, k_hi, k_lo);

  // 5. flash attention -> split bf16 o
  attn_kernel<<<dim3(NHD, 32, 1), 256, 0, stream>>>(q_hi, q_lo, k_hi, k_lo, vT_hi, vT_lo, o_hi, o_lo);

  // 6. h1 = x + o @ w_o^T  (split)
  { GemmP p{}; p.Ah = o_hi; p.aloOff = o_lo - o_hi;
    p.B0h = wo_c; p.blo0 = NQ; p.B1h = wo_c; p.blo1 = NQ; p.ns0 = 1 << 30;
    p.K = DM; p.fixedM = TT; p.maxRow = TT - 1;
    p.oF = h1; p.ldF = 2048; p.addX = x;
    gemm_bt<2, true><<<dim3(16, 16, 1), 256, 0, stream>>>(p); }

  // 7. t = rms(h1, ln2) -> f32 (routing) + bf16 (experts)
  rms_kernel<<<TT, 256, 0, stream>>>(h1, ln2, nullptr, nullptr, t32, t_bf);

  // 8. routing (fp32) + slot assignment
  routing_kernel<<<TT, 64, 0, stream>>>(t32, gw, gb, inds, wvals, ctrl);
  scan_kernel<<<1, 64, 0, stream>>>(ctrl);
  assign_kernel<<<8, 256, 0, stream>>>(inds, wvals, ctrl, perm, wslot, inv);

  // 9. shared expert: gu -> hm -> (down fused into final)
  { GemmP p{}; p.Ah = t_bf; p.B0h = shg_c; p.B1h = shu_c; p.ns0 = 2048; p.K = DM;
    p.fixedM = TT; p.maxRow = TT - 1; p.oB = gu_sh; p.ldB = 4096;
    gemm_bt<3, false><<<dim3(16, 32, 1), 256, 0, stream>>>(p); }
  hm_sh_kernel<<<TT, 256, 0, stream>>>(gu_sh, hm_sh);

  // 10. MoE: gathered g/u GEMM, silu*u*w, down GEMM -> per-slot dtmp
  { GemmP p{}; p.Ah = t_bf; p.permA = perm; p.cnt = ctrl; p.offs = ctrl + 16;
    p.fixedM = TT; p.maxRow = 8191;
    p.B0h = wg_c; p.B1h = wu_c; p.ns0 = 1024; p.bstride = (long)NI * DM; p.K = DM;
    p.oB = gu_moe; p.ldB = 2048;
    gemm_bt<3, false><<<dim3(16, 16, 16), 256, 0, stream>>>(p); }
  hm_moe_kernel<<<8192, 256, 0, stream>>>(gu_moe, wslot, hm_moe);
  { GemmP p{}; p.Ah = hm_moe; p.cnt = ctrl; p.offs = ctrl + 16;
    p.fixedM = TT; p.maxRow = 8191;
    p.B0h = wd_c; p.B1h = wd_c; p.ns0 = 1 << 30; p.bstride = (long)DM * NI; p.K = NI;
    p.oB = dtmp; p.ldB = 2048;
    gemm_bt<3, false><<<dim3(16, 16, 16), 256, 0, stream>>>(p); }

  // 11. out = h1 + Σ dtmp[slots(t)] + hm_sh @ sh_d^T
  { GemmP p{}; p.Ah = hm_sh; p.B0h = shd_c; p.B1h = shd_c; p.ns0 = 1 << 30; p.K = DM;
    p.fixedM = TT; p.maxRow = TT - 1;
    p.oF = out; p.ldF = 2048; p.addX = h1; p.dslots = dtmp; p.inv = inv;
    gemm_bt<5, false><<<dim3(16, 16, 1), 256, 0, stream>>>(p); }
}